// Round 1
// baseline (116.590 us; speedup 1.0000x reference)
//
#include <hip/hip_runtime.h>
#include <hip/hip_bf16.h>
#include <hip/hip_fp16.h>

#define NB 4
#define NS 2048
#define NE 128
#define NH 16
#define ND 8

#define THALF 1024     // t rows staged per phase (2 phases)
#define NCH 32         // chunks of 32 t per phase
#define VSTRIDE 1032   // shorts per vT row (mult of 8 -> 16B-aligned b128; 1032*2/4 % 32 = 4-bank stagger/row)

typedef __attribute__((ext_vector_type(8))) _Float16 half8;
typedef __attribute__((ext_vector_type(4))) float f32x4;

__device__ __forceinline__ unsigned int pkrtz(float a, float b) {
    typedef __fp16 fp16v2 __attribute__((ext_vector_type(2)));
    union { fp16v2 h; unsigned int u; } v;
    v.h = __builtin_amdgcn_cvt_pkrtz(a, b);
    return v.u;
}
__device__ __forceinline__ unsigned short f2h(float a) {
    return __half_as_ushort(__float2half(a));   // RNE
}
__device__ __forceinline__ half8 mk_half8(unsigned u0, unsigned u1,
                                          unsigned u2, unsigned u3) {
    union { half8 h; unsigned u[4]; } v;
    v.u[0] = u0; v.u[1] = u1; v.u[2] = u2; v.u[3] = u3;
    return v.h;
}
__device__ __forceinline__ half8 u4_half8(uint4 u) {
    union { uint4 u4; half8 h; } v; v.u4 = u; return v.h;
}

// cumprod-of-cos row: p[d] = prod_{i<=d} cos(x[i] + th[i])
__device__ __forceinline__ void qrow(const float* __restrict__ xp,
                                     const float* th, float* p) {
    float4 a = *(const float4*)xp, c = *(const float4*)(xp + 4);
    float t = 1.f;
    t *= cosf(a.x + th[0]); p[0] = t;
    t *= cosf(a.y + th[1]); p[1] = t;
    t *= cosf(a.z + th[2]); p[2] = t;
    t *= cosf(a.w + th[3]); p[3] = t;
    t *= cosf(c.x + th[4]); p[4] = t;
    t *= cosf(c.y + th[5]); p[5] = t;
    t *= cosf(c.z + th[6]); p[6] = t;
    t *= cosf(c.w + th[7]); p[7] = t;
}

// One block = one (b,h) x one EIGHTH of query rows (256). 512 thr = 8 waves,
// each wave 2 m-tiles of 16 rows.
//
// R9 change: PHASED t-range. exp2 here has no running-max rescale (|s|<=4.08
// in log2 units), so partial O / denom sums over t-halves add directly in
// registers. Block stages t in [0,1024), runs 32 chunks, barriers, re-stages
// t in [1024,2048) into the SAME LDS. LDS 78336 -> 35008 B => 4 blocks/CU =
// 8 waves/SIMD (was 4): the kernel was running at single-wave dependency-
// chain latency (VALUBusy 57 / MfmaUtil 20 / no pipe >60%).
// kb bias dropped: mask applied by zeroing V^T columns + ones-row entries
// (masked t then contributes 0 to numerator AND denominator); score MFMA C=0.
// bm (own m-rows) computed straight from x in registers, so it needs no LDS
// residency across phases.
//
// TRANSPOSE-FREE pipeline (verified R8): scores computed as S^T via
// mfma(A = q_t-rows, B = q_m-rows, C = 0). C-layout of S^T gives each lane
// P[m=l15][t=tb+4*quad+r] — already A-operand-shaped for the PV MFMA under
// k-permutation pi(8q+j) = 4q + (j&3) + 16*(j>>2); V^T rows are staged
// pi-reordered. q scaled by SC = sqrt(log2e/sqrt(8)) -> exp2 directly; V^T
// ones-row at n=8 yields the softmax denominator as O column 8.
__global__ __launch_bounds__(512, 8) void attn_kernel(
        const float* __restrict__ x,
        const float* __restrict__ theta,
        const int* __restrict__ mask,
        unsigned short* __restrict__ mid) {            // f16 [B*S][NE]
    __shared__ unsigned short qhl[THALF * ND + 24];    // 16,432 B (+24: A-frag overread pad)
    __shared__ unsigned short vT[9 * VSTRIDE];         // 18,576 B: pi-ordered V^T + ones row
                                                       // total 35,008 B -> 4 blocks/CU

    const int bid = blockIdx.x;
    const int bh = bid >> 3;
    const int b = bh >> 4, h = bh & (NH - 1);
    const int meighth = bid & 7;
    const int tid = threadIdx.x;

    const float SC = 0.71421629f;   // sqrt(log2(e)/sqrt(8))

    float th[ND];
#pragma unroll
    for (int d = 0; d < ND; d++) th[d] = theta[d];

    const int wave = tid >> 6, lane = tid & 63;
    const int quad = lane >> 4, l15 = lane & 15;
    const int mbase = meighth * 256 + wave * 32;

    if (tid < 24) qhl[THALF * ND + tid] = 0;   // pad (never contributes: B k>=8 is zero)

    // ---- B operand (own m rows) straight from x; quad 0 holds real k=0..7 ----
    half8 hz = {0, 0, 0, 0, 0, 0, 0, 0};
    half8 bm0, bm1;
    {
        float pm[ND];
        uint4 qa, qb;
        qrow(x + ((size_t)(b * NS + mbase + l15) * NE + h * ND), th, pm);
        qa.x = pkrtz(pm[0] * SC, pm[1] * SC);
        qa.y = pkrtz(pm[2] * SC, pm[3] * SC);
        qa.z = pkrtz(pm[4] * SC, pm[5] * SC);
        qa.w = pkrtz(pm[6] * SC, pm[7] * SC);
        qrow(x + ((size_t)(b * NS + mbase + 16 + l15) * NE + h * ND), th, pm);
        qb.x = pkrtz(pm[0] * SC, pm[1] * SC);
        qb.y = pkrtz(pm[2] * SC, pm[3] * SC);
        qb.z = pkrtz(pm[4] * SC, pm[5] * SC);
        qb.w = pkrtz(pm[6] * SC, pm[7] * SC);
        bm0 = quad ? hz : u4_half8(qa);
        bm1 = quad ? hz : u4_half8(qb);
    }

    const int vrow = (l15 < 9) ? l15 : 8;
    const unsigned short* vbase = &vT[vrow * VSTRIDE];

    f32x4 O0 = {0.f, 0.f, 0.f, 0.f}, O1 = {0.f, 0.f, 0.f, 0.f};
    const f32x4 zc = {0.f, 0.f, 0.f, 0.f};

    for (int ph = 0; ph < 2; ph++) {
        // ---- stage this t-half: each thread stages one pi-pair (2 rows) ----
        {
            int chs = tid >> 4, i = tid & 15;
            int ta = 4 * (i >> 2) + 2 * (i & 1) + 16 * ((i >> 1) & 1);
            int r0 = chs * 32 + ta, r1 = r0 + 1;        // local rows in [0,1024)
            int g0 = ph * THALF + r0;                    // global t rows
            float p0[ND], p1[ND];
            qrow(x + ((size_t)(b * NS + g0) * NE + h * ND), th, p0);
            qrow(x + ((size_t)(b * NS + g0 + 1) * NE + h * ND), th, p1);
            float mz0 = mask[b * NS + g0] ? 1.f : 0.f;
            float mz1 = mask[b * NS + g0 + 1] ? 1.f : 0.f;
            uint4 qa, qb;
            qa.x = pkrtz(p0[0] * SC, p0[1] * SC);
            qa.y = pkrtz(p0[2] * SC, p0[3] * SC);
            qa.z = pkrtz(p0[4] * SC, p0[5] * SC);
            qa.w = pkrtz(p0[6] * SC, p0[7] * SC);
            qb.x = pkrtz(p1[0] * SC, p1[1] * SC);
            qb.y = pkrtz(p1[2] * SC, p1[3] * SC);
            qb.z = pkrtz(p1[4] * SC, p1[5] * SC);
            qb.w = pkrtz(p1[6] * SC, p1[7] * SC);
            *(uint4*)&qhl[r0 * ND] = qa;
            *(uint4*)&qhl[r1 * ND] = qb;
#pragma unroll
            for (int d = 0; d < ND; d++)
                *(unsigned int*)&vT[d * VSTRIDE + chs * 32 + 2 * i] =
                    pkrtz(p0[d] * mz0, p1[d] * mz1);
            // ones row carries the mask: masked t excluded from denominator too
            *(unsigned int*)&vT[8 * VSTRIDE + chs * 32 + 2 * i] = pkrtz(mz0, mz1);
        }
        __syncthreads();

        // ---- 32 chunks of this half; O keeps accumulating across phases ----
        for (int ch = 0; ch < NCH; ch++) {
            int tb = ch * 32;
            // A operand (q_t): quad>0 slots read neighbor rows (garbage) — zeroed by B.
            half8 at0 = *(const half8*)&qhl[(tb + l15) * ND + quad * 8];
            half8 at1 = *(const half8*)&qhl[(tb + 16 + l15) * ND + quad * 8];
            half8 vf  = *(const half8*)&vbase[tb + quad * 8];

            // S^T tiles: rows t, cols m = l15
            f32x4 s00 = __builtin_amdgcn_mfma_f32_16x16x32_f16(at0, bm0, zc, 0, 0, 0);
            f32x4 s01 = __builtin_amdgcn_mfma_f32_16x16x32_f16(at0, bm1, zc, 0, 0, 0);
            f32x4 s10 = __builtin_amdgcn_mfma_f32_16x16x32_f16(at1, bm0, zc, 0, 0, 0);
            f32x4 s11 = __builtin_amdgcn_mfma_f32_16x16x32_f16(at1, bm1, zc, 0, 0, 0);

            // exp2 + in-lane pack -> PV A-frags (k-order = pi)
            half8 pA0 = mk_half8(
                pkrtz(__builtin_amdgcn_exp2f(s00[0]), __builtin_amdgcn_exp2f(s00[1])),
                pkrtz(__builtin_amdgcn_exp2f(s00[2]), __builtin_amdgcn_exp2f(s00[3])),
                pkrtz(__builtin_amdgcn_exp2f(s10[0]), __builtin_amdgcn_exp2f(s10[1])),
                pkrtz(__builtin_amdgcn_exp2f(s10[2]), __builtin_amdgcn_exp2f(s10[3])));
            half8 pA1 = mk_half8(
                pkrtz(__builtin_amdgcn_exp2f(s01[0]), __builtin_amdgcn_exp2f(s01[1])),
                pkrtz(__builtin_amdgcn_exp2f(s01[2]), __builtin_amdgcn_exp2f(s01[3])),
                pkrtz(__builtin_amdgcn_exp2f(s11[0]), __builtin_amdgcn_exp2f(s11[1])),
                pkrtz(__builtin_amdgcn_exp2f(s11[2]), __builtin_amdgcn_exp2f(s11[3])));

            O0 = __builtin_amdgcn_mfma_f32_16x16x32_f16(pA0, vf, O0, 0, 0, 0);
            O1 = __builtin_amdgcn_mfma_f32_16x16x32_f16(pA1, vf, O1, 0, 0, 0);
        }
        __syncthreads();   // all waves done reading before re-stage
    }

    // ---- epilogue: l = column 8 of O; normalize; f16 store ----
#pragma unroll
    for (int mt = 0; mt < 2; mt++) {
        f32x4 O = mt ? O1 : O0;
#pragma unroll
        for (int r = 0; r < 4; r++) {
            float lsum = __shfl(O[r], (lane & 48) | 8, 64);
            float v = O[r] / lsum;
            if (l15 < ND) {
                int m = mbase + mt * 16 + quad * 4 + r;
                mid[(size_t)(b * NS + m) * NE + h * ND + l15] = f2h(v);
            }
        }
    }
}

// out = mid(f16) @ w^T, f16 MFMA. Block: 32 m-rows x full N=128; 4 waves.
__global__ __launch_bounds__(256) void proj_kernel(
        const unsigned short* __restrict__ mid,
        const float* __restrict__ w,
        float* __restrict__ out) {
    __shared__ unsigned short wf[NE * 136];
    __shared__ unsigned short am[32 * 136];
    const int rb = blockIdx.x * 32;
    const int tid = threadIdx.x;

    for (int i = tid; i < 2048; i += 256) {   // wf[n][k] = f16(w[n][k])
        const float* wp = w + i * 8;
        float4 a = *(const float4*)wp, c = *(const float4*)(wp + 4);
        uint4 pk;
        pk.x = pkrtz(a.x, a.y); pk.y = pkrtz(a.z, a.w);
        pk.z = pkrtz(c.x, c.y); pk.w = pkrtz(c.z, c.w);
        int n = i >> 4, k8 = (i & 15) * 8;
        *(uint4*)&wf[n * 136 + k8] = pk;
    }
    for (int i = tid; i < 512; i += 256) {    // am[r][k] = mid[rb+r][k]
        int r = i >> 4, k8 = (i & 15) * 8;
        uint4 v = *(const uint4*)&mid[(size_t)(rb + r) * NE + k8];
        *(uint4*)&am[r * 136 + k8] = v;
    }
    __syncthreads();

    const int wave = tid >> 6, lane = tid & 63;
    const int quad = lane >> 4, l15 = lane & 15;
    const int mt = wave & 1, nh = wave >> 1;

    half8 af[4];
#pragma unroll
    for (int kt = 0; kt < 4; kt++)
        af[kt] = *(const half8*)&am[(mt * 16 + l15) * 136 + kt * 32 + quad * 8];

#pragma unroll
    for (int nt = 0; nt < 4; nt++) {
        int n0 = (nh * 4 + nt) * 16;
        f32x4 acc = {0.f, 0.f, 0.f, 0.f};
#pragma unroll
        for (int kt = 0; kt < 4; kt++) {
            half8 bf = *(const half8*)&wf[(n0 + l15) * 136 + kt * 32 + quad * 8];
            acc = __builtin_amdgcn_mfma_f32_16x16x32_f16(af[kt], bf, acc, 0, 0, 0);
        }
#pragma unroll
        for (int r = 0; r < 4; r++)
            out[(size_t)(rb + mt * 16 + quad * 4 + r) * NE + n0 + l15] = acc[r];
    }
}

extern "C" void kernel_launch(void* const* d_in, const int* in_sizes, int n_in,
                              void* d_out, int out_size, void* d_ws, size_t ws_size,
                              hipStream_t stream) {
    const float* x     = (const float*)d_in[0];
    const float* theta = (const float*)d_in[1];
    const float* w_out = (const float*)d_in[2];
    const int*   mask  = (const int*)d_in[3];
    float* out = (float*)d_out;

    unsigned short* mid16 = (unsigned short*)d_ws;   // f16 [B*S][NE] = 2 MB

    attn_kernel<<<NB * NH * 8, 512, 0, stream>>>(x, theta, mask, mid16);
    proj_kernel<<<NB * NS / 32, 256, 0, stream>>>(mid16, w_out, out);
}

// Round 2
// 106.214 us; speedup vs baseline: 1.0977x; 1.0977x over previous
//
#include <hip/hip_runtime.h>
#include <hip/hip_bf16.h>
#include <hip/hip_fp16.h>

#define NB 4
#define NS 2048
#define NE 128
#define NH 16
#define ND 8

#define THALF 1024     // t rows staged per phase (2 phases)
#define NCH 32         // chunks of 32 t per phase
#define VSTRIDE 1032   // shorts per vT row (mult of 8 -> 16B-aligned b128; 1032*2/4 % 32 = 4-bank stagger/row)

typedef __attribute__((ext_vector_type(8))) _Float16 half8;
typedef __attribute__((ext_vector_type(4))) float f32x4;

__device__ __forceinline__ unsigned int pkrtz(float a, float b) {
    typedef __fp16 fp16v2 __attribute__((ext_vector_type(2)));
    union { fp16v2 h; unsigned int u; } v;
    v.h = __builtin_amdgcn_cvt_pkrtz(a, b);
    return v.u;
}
__device__ __forceinline__ unsigned short f2h(float a) {
    return __half_as_ushort(__float2half(a));   // RNE
}
__device__ __forceinline__ half8 mk_half8(unsigned u0, unsigned u1,
                                          unsigned u2, unsigned u3) {
    union { half8 h; unsigned u[4]; } v;
    v.u[0] = u0; v.u[1] = u1; v.u[2] = u2; v.u[3] = u3;
    return v.h;
}

// cumprod-of-cos row: p[d] = prod_{i<=d} cos(x[i] + th[i])
__device__ __forceinline__ void qrow(const float* __restrict__ xp,
                                     const float* th, float* p) {
    float4 a = *(const float4*)xp, c = *(const float4*)(xp + 4);
    float t = 1.f;
    t *= cosf(a.x + th[0]); p[0] = t;
    t *= cosf(a.y + th[1]); p[1] = t;
    t *= cosf(a.z + th[2]); p[2] = t;
    t *= cosf(a.w + th[3]); p[3] = t;
    t *= cosf(c.x + th[4]); p[4] = t;
    t *= cosf(c.y + th[5]); p[5] = t;
    t *= cosf(c.z + th[6]); p[6] = t;
    t *= cosf(c.w + th[7]); p[7] = t;
}

// One block = one (b,h) x one EIGHTH of query rows (256). 512 thr = 8 waves,
// each wave 2 m-tiles of 16 rows.
//
// R10: phased t-range KEPT (LDS 35 KB -> 4 blocks/CU), R9's spill regression
// fixed. R9's __launch_bounds__(512,8) capped the unified VGPR+AGPR budget at
// 64/wave -> allocator gave 32 arch VGPRs -> scratch spills (WRITE_SIZE
// 2 MB -> 56 MB). Now (512,6): budget ~85, natural footprint ~52+acc fits.
// bm is NOT recomputed from x (R9's extra register pressure): each block
// processes its OWN t-half first (tph = bph ^ p; summation order over t is
// free — no running-max rescale), so its m-rows are in qhl after the first
// staging barrier and bm loads from LDS exactly as in R8.
// Mask is folded into V^T (zeroed cols + zeroed ones-row entries): masked t
// contributes 0 to numerator and denominator; score MFMAs take C = 0.
//
// TRANSPOSE-FREE pipeline (verified R8): scores computed as S^T via
// mfma(A = q_t-rows, B = q_m-rows, C = 0). C-layout of S^T gives each lane
// P[m=l15][t=tb+4*quad+r] — already A-operand-shaped for the PV MFMA under
// k-permutation pi(8q+j) = 4q + (j&3) + 16*(j>>2); V^T rows are staged
// pi-reordered. q scaled by SC = sqrt(log2e/sqrt(8)) -> exp2 directly; V^T
// ones-row at n=8 yields the softmax denominator as O column 8.
__global__ __launch_bounds__(512, 6) void attn_kernel(
        const float* __restrict__ x,
        const float* __restrict__ theta,
        const int* __restrict__ mask,
        unsigned short* __restrict__ mid) {            // f16 [B*S][NE]
    __shared__ unsigned short qhl[THALF * ND + 24];    // 16,432 B (+24: A-frag overread pad)
    __shared__ unsigned short vT[9 * VSTRIDE];         // 18,576 B: pi-ordered V^T + ones row
                                                       // total 35,008 B -> 4 blocks/CU

    const int bid = blockIdx.x;
    const int bh = bid >> 3;
    const int b = bh >> 4, h = bh & (NH - 1);
    const int meighth = bid & 7;
    const int tid = threadIdx.x;

    const float SC = 0.71421629f;   // sqrt(log2(e)/sqrt(8))

    float th[ND];
#pragma unroll
    for (int d = 0; d < ND; d++) th[d] = theta[d];

    const int wave = tid >> 6, lane = tid & 63;
    const int quad = lane >> 4, l15 = lane & 15;
    const int mbase = meighth * 256 + wave * 32;
    const int bph = meighth >> 2;                       // t-half containing our m rows
    const int lmb = (meighth & 3) * 256 + wave * 32;    // local row of m-base in that half

    if (tid < 24) qhl[THALF * ND + tid] = 0;   // pad (never contributes: B k>=8 is zero)

    half8 hz = {0, 0, 0, 0, 0, 0, 0, 0};
    half8 bm0 = hz, bm1 = hz;                  // loaded from LDS after first staging

    const int vrow = (l15 < 9) ? l15 : 8;
    const unsigned short* vbase = &vT[vrow * VSTRIDE];

    f32x4 O0 = {0.f, 0.f, 0.f, 0.f}, O1 = {0.f, 0.f, 0.f, 0.f};
    const f32x4 zc = {0.f, 0.f, 0.f, 0.f};

    for (int p = 0; p < 2; p++) {
        const int tph = bph ^ p;   // own half first: bm rows resident at p == 0
        // ---- stage this t-half: each thread stages one pi-pair (2 rows) ----
        {
            int chs = tid >> 4, i = tid & 15;
            int ta = 4 * (i >> 2) + 2 * (i & 1) + 16 * ((i >> 1) & 1);
            int r0 = chs * 32 + ta, r1 = r0 + 1;        // local rows in [0,1024)
            int g0 = tph * THALF + r0;                   // global t rows
            float p0[ND], p1[ND];
            qrow(x + ((size_t)(b * NS + g0) * NE + h * ND), th, p0);
            qrow(x + ((size_t)(b * NS + g0 + 1) * NE + h * ND), th, p1);
            float mz0 = mask[b * NS + g0] ? 1.f : 0.f;
            float mz1 = mask[b * NS + g0 + 1] ? 1.f : 0.f;
            uint4 qa, qb;
            qa.x = pkrtz(p0[0] * SC, p0[1] * SC);
            qa.y = pkrtz(p0[2] * SC, p0[3] * SC);
            qa.z = pkrtz(p0[4] * SC, p0[5] * SC);
            qa.w = pkrtz(p0[6] * SC, p0[7] * SC);
            qb.x = pkrtz(p1[0] * SC, p1[1] * SC);
            qb.y = pkrtz(p1[2] * SC, p1[3] * SC);
            qb.z = pkrtz(p1[4] * SC, p1[5] * SC);
            qb.w = pkrtz(p1[6] * SC, p1[7] * SC);
            *(uint4*)&qhl[r0 * ND] = qa;
            *(uint4*)&qhl[r1 * ND] = qb;
#pragma unroll
            for (int d = 0; d < ND; d++)
                *(unsigned int*)&vT[d * VSTRIDE + chs * 32 + 2 * i] =
                    pkrtz(p0[d] * mz0, p1[d] * mz1);
            // ones row carries the mask: masked t excluded from denominator too
            *(unsigned int*)&vT[8 * VSTRIDE + chs * 32 + 2 * i] = pkrtz(mz0, mz1);
        }
        __syncthreads();

        if (p == 0) {
            // B operand (own m rows) from LDS; quad 0 holds real k=0..7, rest zero.
            bm0 = quad ? hz : *(const half8*)&qhl[(lmb + l15) * ND];
            bm1 = quad ? hz : *(const half8*)&qhl[(lmb + 16 + l15) * ND];
        }

        // ---- 32 chunks of this half; O keeps accumulating across phases ----
        for (int ch = 0; ch < NCH; ch++) {
            int tb = ch * 32;
            // A operand (q_t): quad>0 slots read neighbor rows (garbage) — zeroed by B.
            half8 at0 = *(const half8*)&qhl[(tb + l15) * ND + quad * 8];
            half8 at1 = *(const half8*)&qhl[(tb + 16 + l15) * ND + quad * 8];
            half8 vf  = *(const half8*)&vbase[tb + quad * 8];

            // S^T tiles: rows t, cols m = l15
            f32x4 s00 = __builtin_amdgcn_mfma_f32_16x16x32_f16(at0, bm0, zc, 0, 0, 0);
            f32x4 s01 = __builtin_amdgcn_mfma_f32_16x16x32_f16(at0, bm1, zc, 0, 0, 0);
            f32x4 s10 = __builtin_amdgcn_mfma_f32_16x16x32_f16(at1, bm0, zc, 0, 0, 0);
            f32x4 s11 = __builtin_amdgcn_mfma_f32_16x16x32_f16(at1, bm1, zc, 0, 0, 0);

            // exp2 + in-lane pack -> PV A-frags (k-order = pi)
            half8 pA0 = mk_half8(
                pkrtz(__builtin_amdgcn_exp2f(s00[0]), __builtin_amdgcn_exp2f(s00[1])),
                pkrtz(__builtin_amdgcn_exp2f(s00[2]), __builtin_amdgcn_exp2f(s00[3])),
                pkrtz(__builtin_amdgcn_exp2f(s10[0]), __builtin_amdgcn_exp2f(s10[1])),
                pkrtz(__builtin_amdgcn_exp2f(s10[2]), __builtin_amdgcn_exp2f(s10[3])));
            half8 pA1 = mk_half8(
                pkrtz(__builtin_amdgcn_exp2f(s01[0]), __builtin_amdgcn_exp2f(s01[1])),
                pkrtz(__builtin_amdgcn_exp2f(s01[2]), __builtin_amdgcn_exp2f(s01[3])),
                pkrtz(__builtin_amdgcn_exp2f(s11[0]), __builtin_amdgcn_exp2f(s11[1])),
                pkrtz(__builtin_amdgcn_exp2f(s11[2]), __builtin_amdgcn_exp2f(s11[3])));

            O0 = __builtin_amdgcn_mfma_f32_16x16x32_f16(pA0, vf, O0, 0, 0, 0);
            O1 = __builtin_amdgcn_mfma_f32_16x16x32_f16(pA1, vf, O1, 0, 0, 0);
        }
        __syncthreads();   // all waves done reading before re-stage
    }

    // ---- epilogue: l = column 8 of O; normalize; f16 store ----
#pragma unroll
    for (int mt = 0; mt < 2; mt++) {
        f32x4 O = mt ? O1 : O0;
#pragma unroll
        for (int r = 0; r < 4; r++) {
            float lsum = __shfl(O[r], (lane & 48) | 8, 64);
            float v = O[r] / lsum;
            if (l15 < ND) {
                int m = mbase + mt * 16 + quad * 4 + r;
                mid[(size_t)(b * NS + m) * NE + h * ND + l15] = f2h(v);
            }
        }
    }
}

// out = mid(f16) @ w^T, f16 MFMA. Block: 32 m-rows x full N=128; 4 waves.
__global__ __launch_bounds__(256) void proj_kernel(
        const unsigned short* __restrict__ mid,
        const float* __restrict__ w,
        float* __restrict__ out) {
    __shared__ unsigned short wf[NE * 136];
    __shared__ unsigned short am[32 * 136];
    const int rb = blockIdx.x * 32;
    const int tid = threadIdx.x;

    for (int i = tid; i < 2048; i += 256) {   // wf[n][k] = f16(w[n][k])
        const float* wp = w + i * 8;
        float4 a = *(const float4*)wp, c = *(const float4*)(wp + 4);
        uint4 pk;
        pk.x = pkrtz(a.x, a.y); pk.y = pkrtz(a.z, a.w);
        pk.z = pkrtz(c.x, c.y); pk.w = pkrtz(c.z, c.w);
        int n = i >> 4, k8 = (i & 15) * 8;
        *(uint4*)&wf[n * 136 + k8] = pk;
    }
    for (int i = tid; i < 512; i += 256) {    // am[r][k] = mid[rb+r][k]
        int r = i >> 4, k8 = (i & 15) * 8;
        uint4 v = *(const uint4*)&mid[(size_t)(rb + r) * NE + k8];
        *(uint4*)&am[r * 136 + k8] = v;
    }
    __syncthreads();

    const int wave = tid >> 6, lane = tid & 63;
    const int quad = lane >> 4, l15 = lane & 15;
    const int mt = wave & 1, nh = wave >> 1;

    half8 af[4];
#pragma unroll
    for (int kt = 0; kt < 4; kt++)
        af[kt] = *(const half8*)&am[(mt * 16 + l15) * 136 + kt * 32 + quad * 8];

#pragma unroll
    for (int nt = 0; nt < 4; nt++) {
        int n0 = (nh * 4 + nt) * 16;
        f32x4 acc = {0.f, 0.f, 0.f, 0.f};
#pragma unroll
        for (int kt = 0; kt < 4; kt++) {
            half8 bf = *(const half8*)&wf[(n0 + l15) * 136 + kt * 32 + quad * 8];
            acc = __builtin_amdgcn_mfma_f32_16x16x32_f16(af[kt], bf, acc, 0, 0, 0);
        }
#pragma unroll
        for (int r = 0; r < 4; r++)
            out[(size_t)(rb + mt * 16 + quad * 4 + r) * NE + n0 + l15] = acc[r];
    }
}

extern "C" void kernel_launch(void* const* d_in, const int* in_sizes, int n_in,
                              void* d_out, int out_size, void* d_ws, size_t ws_size,
                              hipStream_t stream) {
    const float* x     = (const float*)d_in[0];
    const float* theta = (const float*)d_in[1];
    const float* w_out = (const float*)d_in[2];
    const int*   mask  = (const int*)d_in[3];
    float* out = (float*)d_out;

    unsigned short* mid16 = (unsigned short*)d_ws;   // f16 [B*S][NE] = 2 MB

    attn_kernel<<<NB * NH * 8, 512, 0, stream>>>(x, theta, mask, mid16);
    proj_kernel<<<NB * NS / 32, 256, 0, stream>>>(mid16, w_out, out);
}

// Round 4
// 103.818 us; speedup vs baseline: 1.1230x; 1.0231x over previous
//
#include <hip/hip_runtime.h>
#include <hip/hip_bf16.h>
#include <hip/hip_fp16.h>

#define NB 4
#define NS 2048
#define NE 128
#define NH 16
#define ND 8

#define THALF 1024     // t rows staged per phase (2 phases)
#define NCH 32         // chunks of 32 t per phase
#define VSTRIDE 1032   // LDS vT row stride (shorts): 16B-aligned, 4-bank stagger/row
#define VGSTR 2056     // global vT row stride (shorts): 2048 + 8 pad, 16B-aligned

typedef __attribute__((ext_vector_type(8))) _Float16 half8;
typedef __attribute__((ext_vector_type(4))) _Float16 half4;
typedef __attribute__((ext_vector_type(4))) float f32x4;

__device__ __forceinline__ unsigned int pkrtz(float a, float b) {
    typedef __fp16 fp16v2 __attribute__((ext_vector_type(2)));
    union { fp16v2 h; unsigned int u; } v;
    v.h = __builtin_amdgcn_cvt_pkrtz(a, b);
    return v.u;
}
__device__ __forceinline__ unsigned short f2h(float a) {
    return __half_as_ushort(__float2half(a));   // RNE
}
__device__ __forceinline__ half8 mk_half8(unsigned u0, unsigned u1,
                                          unsigned u2, unsigned u3) {
    union { half8 h; unsigned u[4]; } v;
    v.u[0] = u0; v.u[1] = u1; v.u[2] = u2; v.u[3] = u3;
    return v.h;
}

// cumprod-of-cos row: p[d] = prod_{i<=d} cos(x[i] + th[i])
__device__ __forceinline__ void qrow(const float* __restrict__ xp,
                                     const float* th, float* p) {
    float4 a = *(const float4*)xp, c = *(const float4*)(xp + 4);
    float t = 1.f;
    t *= cosf(a.x + th[0]); p[0] = t;
    t *= cosf(a.y + th[1]); p[1] = t;
    t *= cosf(a.z + th[2]); p[2] = t;
    t *= cosf(a.w + th[3]); p[3] = t;
    t *= cosf(c.x + th[4]); p[4] = t;
    t *= cosf(c.y + th[5]); p[5] = t;
    t *= cosf(c.z + th[6]); p[6] = t;
    t *= cosf(c.w + th[7]); p[7] = t;
}

// R11 qgen: q computed ONCE per (b,h,s) (was 8x redundant inside attn blocks;
// that cos work was ~half of attn's VALUBusy and drove the spill-prone
// register peak). Writes:
//   qg [b][h][s][d]  f16, pre-scaled by SC  (head-major -> attn stages by memcpy)
//   vtg [b][h][9][VGSTR] f16, pi-reordered + mask-folded + ones row = the
//       exact LDS vT image (per-half columns), so attn staging is a raw copy.
__global__ __launch_bounds__(256) void qgen_kernel(
        const float* __restrict__ x,
        const float* __restrict__ theta,
        const int* __restrict__ mask,
        unsigned short* __restrict__ qg,
        unsigned short* __restrict__ vtg) {
    const int gid = blockIdx.x * 256 + threadIdx.x;   // 0..65535: (b, pair j, h)
    const int b = gid >> 14;
    const int h = gid & (NH - 1);
    const int j = (gid >> 4) & 1023;    // pair within (b,h); s0 = 2j (h fastest -> coalesced x reads)
    const int s0 = 2 * j;
    const float SC = 0.71421629f;       // sqrt(log2(e)/sqrt(8))

    float th[ND];
#pragma unroll
    for (int d = 0; d < ND; d++) th[d] = theta[d];

    float p0[ND], p1[ND];
    qrow(x + ((size_t)(b * NS + s0) * NE + h * ND), th, p0);
    qrow(x + ((size_t)(b * NS + s0 + 1) * NE + h * ND), th, p1);
    const float mz0 = mask[b * NS + s0] ? 1.f : 0.f;
    const float mz1 = mask[b * NS + s0 + 1] ? 1.f : 0.f;
    const int bh = b * NH + h;

    uint4 qa, qb;
    qa.x = pkrtz(p0[0] * SC, p0[1] * SC);
    qa.y = pkrtz(p0[2] * SC, p0[3] * SC);
    qa.z = pkrtz(p0[4] * SC, p0[5] * SC);
    qa.w = pkrtz(p0[6] * SC, p0[7] * SC);
    qb.x = pkrtz(p1[0] * SC, p1[1] * SC);
    qb.y = pkrtz(p1[2] * SC, p1[3] * SC);
    qb.z = pkrtz(p1[4] * SC, p1[5] * SC);
    qb.w = pkrtz(p1[6] * SC, p1[7] * SC);
    *(uint4*)&qg[((size_t)bh * NS + s0) * ND] = qa;
    *(uint4*)&qg[((size_t)bh * NS + s0 + 1) * ND] = qb;

    // pi position within this half: ta = 4*(i>>2)+2*(i&1)+16*((i>>1)&1) inverted
    const int H = s0 >> 10, r0 = s0 & 1023;
    const int chs = r0 >> 5, u = (r0 & 31) >> 1;
    const int i = (u & 1) | (((u >> 3) & 1) << 1) | (((u >> 1) & 3) << 2);
    const int col = H * THALF + chs * 32 + 2 * i;
    unsigned short* vb = vtg + (size_t)bh * 9 * VGSTR + col;
#pragma unroll
    for (int d = 0; d < ND; d++)
        *(unsigned int*)&vb[d * VGSTR] = pkrtz(p0[d] * mz0, p1[d] * mz1);
    *(unsigned int*)&vb[8 * VGSTR] = pkrtz(mz0, mz1);   // ones row carries mask
}

// One block = one (b,h) x one EIGHTH of query rows (256). 512 thr = 8 waves,
// each wave 2 m-tiles of 16 rows; phased t (2 halves re-staged into same LDS;
// no running-max rescale -> partial sums add directly).
//
// R11: staging is now a pure coalesced uint4 copy from qgen's outputs (no cos,
// no pkrtz, no pressure spike -> no launch_bounds cap, no spills).
// Score MFMAs use 16x16x16f16 (k=16 covers the 8 real k): A-frag is b64, so
// the two q_t reads halve; per-chunk-wave LDS traffic 3 KB -> 2 KB. The x16
// C-layout == x32 C-layout, so the verified pi-packing into the PV A-frag is
// unchanged: lane holds P[m=l15][t=tb+4*quad+r]; pi(8q+jj)=4q+(jj&3)+16*(jj>>2);
// V^T rows pre-permuted by pi (in qgen). Ones-row at n=8 -> denominator in
// O column 8. bm (own m rows) loads once from global qg (b64, quads 0,1).
__global__ __launch_bounds__(512) void attn_kernel(
        const unsigned short* __restrict__ qg,
        const unsigned short* __restrict__ vtg,
        unsigned short* __restrict__ mid) {            // f16 [B*S][NE]
    __shared__ unsigned short qhl[THALF * ND + 24];    // 16,432 B (+24: A-frag overread pad)
    __shared__ unsigned short vT[9 * VSTRIDE];         // 18,576 B
                                                       // total 35,008 B

    const int bid = blockIdx.x;
    const int bh = bid >> 3;
    const int b = bh >> 4, h = bh & (NH - 1);
    const int meighth = bid & 7;
    const int tid = threadIdx.x;

    const int wave = tid >> 6, lane = tid & 63;
    const int quad = lane >> 4, l15 = lane & 15;
    const int mbase = meighth * 256 + wave * 32;

    if (tid < 24) qhl[THALF * ND + tid] = 0;   // pad (never contributes)

    // B operand (own m rows) from global qg: 16x16x16 B-frag = 4 f16, k=quad*4+j.
    // quads 0,1 real (k=0..7); quads 2,3 zero (kills the A garbage half).
    half4 hz4 = {0, 0, 0, 0};
    const unsigned short* qmrow = qg + ((size_t)bh * NS + mbase + l15) * ND
                                + (quad < 2 ? quad * 4 : 0);
    half4 bm0 = (quad < 2) ? *(const half4*)qmrow : hz4;
    half4 bm1 = (quad < 2) ? *(const half4*)(qmrow + 16 * ND) : hz4;

    const int vrow = (l15 < 9) ? l15 : 8;
    const unsigned short* vbase = &vT[vrow * VSTRIDE];

    f32x4 O0 = {0.f, 0.f, 0.f, 0.f}, O1 = {0.f, 0.f, 0.f, 0.f};
    const f32x4 zc = {0.f, 0.f, 0.f, 0.f};

    for (int p = 0; p < 2; p++) {
        // ---- stage this t-half: pure copies ----
        {   // qhl: 1024 rows x 16B = 1024 uint4, contiguous
            const uint4* qs = (const uint4*)(qg + ((size_t)bh * NS + p * THALF) * ND);
            uint4* qd = (uint4*)qhl;
            qd[tid] = qs[tid];
            qd[tid + 512] = qs[tid + 512];
        }
        {   // vT: 9 rows x 1024 shorts = 1152 uint4
            const unsigned short* vs = vtg + (size_t)bh * 9 * VGSTR + p * THALF;
            for (int jj = tid; jj < 1152; jj += 512) {
                int d = jj >> 7, c = (jj & 127) << 3;
                *(uint4*)&vT[d * VSTRIDE + c] = *(const uint4*)&vs[d * VGSTR + c];
            }
        }
        __syncthreads();

        // ---- 32 chunks of this half; O keeps accumulating across phases ----
        for (int ch = 0; ch < NCH; ch++) {
            int tb = ch * 32;
            // A operand (q_t) b64: quads 0,1 = row halves (k 0..7); quads 2,3
            // read the next row (garbage) — zeroed by B.
            half4 at0 = *(const half4*)&qhl[(tb + l15) * ND + quad * 4];
            half4 at1 = *(const half4*)&qhl[(tb + 16 + l15) * ND + quad * 4];
            half8 vf  = *(const half8*)&vbase[tb + quad * 8];

            // S^T tiles (16x16x16; C-layout identical to x32): rows t, cols m=l15
            f32x4 s00 = __builtin_amdgcn_mfma_f32_16x16x16f16(at0, bm0, zc, 0, 0, 0);
            f32x4 s01 = __builtin_amdgcn_mfma_f32_16x16x16f16(at0, bm1, zc, 0, 0, 0);
            f32x4 s10 = __builtin_amdgcn_mfma_f32_16x16x16f16(at1, bm0, zc, 0, 0, 0);
            f32x4 s11 = __builtin_amdgcn_mfma_f32_16x16x16f16(at1, bm1, zc, 0, 0, 0);

            // exp2 + in-lane pack -> PV A-frags (k-order = pi)
            half8 pA0 = mk_half8(
                pkrtz(__builtin_amdgcn_exp2f(s00[0]), __builtin_amdgcn_exp2f(s00[1])),
                pkrtz(__builtin_amdgcn_exp2f(s00[2]), __builtin_amdgcn_exp2f(s00[3])),
                pkrtz(__builtin_amdgcn_exp2f(s10[0]), __builtin_amdgcn_exp2f(s10[1])),
                pkrtz(__builtin_amdgcn_exp2f(s10[2]), __builtin_amdgcn_exp2f(s10[3])));
            half8 pA1 = mk_half8(
                pkrtz(__builtin_amdgcn_exp2f(s01[0]), __builtin_amdgcn_exp2f(s01[1])),
                pkrtz(__builtin_amdgcn_exp2f(s01[2]), __builtin_amdgcn_exp2f(s01[3])),
                pkrtz(__builtin_amdgcn_exp2f(s11[0]), __builtin_amdgcn_exp2f(s11[1])),
                pkrtz(__builtin_amdgcn_exp2f(s11[2]), __builtin_amdgcn_exp2f(s11[3])));

            O0 = __builtin_amdgcn_mfma_f32_16x16x32_f16(pA0, vf, O0, 0, 0, 0);
            O1 = __builtin_amdgcn_mfma_f32_16x16x32_f16(pA1, vf, O1, 0, 0, 0);
        }
        __syncthreads();   // all waves done reading before re-stage
    }

    // ---- epilogue: l = column 8 of O; normalize; f16 store ----
#pragma unroll
    for (int mt = 0; mt < 2; mt++) {
        f32x4 O = mt ? O1 : O0;
#pragma unroll
        for (int r = 0; r < 4; r++) {
            float lsum = __shfl(O[r], (lane & 48) | 8, 64);
            float v = O[r] / lsum;
            if (l15 < ND) {
                int m = mbase + mt * 16 + quad * 4 + r;
                mid[(size_t)(b * NS + m) * NE + h * ND + l15] = f2h(v);
            }
        }
    }
}

// out = mid(f16) @ w^T, f16 MFMA. Block: 32 m-rows x full N=128; 4 waves.
__global__ __launch_bounds__(256) void proj_kernel(
        const unsigned short* __restrict__ mid,
        const float* __restrict__ w,
        float* __restrict__ out) {
    __shared__ unsigned short wf[NE * 136];
    __shared__ unsigned short am[32 * 136];
    const int rb = blockIdx.x * 32;
    const int tid = threadIdx.x;

    for (int i = tid; i < 2048; i += 256) {   // wf[n][k] = f16(w[n][k])
        const float* wp = w + i * 8;
        float4 a = *(const float4*)wp, c = *(const float4*)(wp + 4);
        uint4 pk;
        pk.x = pkrtz(a.x, a.y); pk.y = pkrtz(a.z, a.w);
        pk.z = pkrtz(c.x, c.y); pk.w = pkrtz(c.z, c.w);
        int n = i >> 4, k8 = (i & 15) * 8;
        *(uint4*)&wf[n * 136 + k8] = pk;
    }
    for (int i = tid; i < 512; i += 256) {    // am[r][k] = mid[rb+r][k]
        int r = i >> 4, k8 = (i & 15) * 8;
        uint4 v = *(const uint4*)&mid[(size_t)(rb + r) * NE + k8];
        *(uint4*)&am[r * 136 + k8] = v;
    }
    __syncthreads();

    const int wave = tid >> 6, lane = tid & 63;
    const int quad = lane >> 4, l15 = lane & 15;
    const int mt = wave & 1, nh = wave >> 1;

    half8 af[4];
#pragma unroll
    for (int kt = 0; kt < 4; kt++)
        af[kt] = *(const half8*)&am[(mt * 16 + l15) * 136 + kt * 32 + quad * 8];

#pragma unroll
    for (int nt = 0; nt < 4; nt++) {
        int n0 = (nh * 4 + nt) * 16;
        f32x4 acc = {0.f, 0.f, 0.f, 0.f};
#pragma unroll
        for (int kt = 0; kt < 4; kt++) {
            half8 bf = *(const half8*)&wf[(n0 + l15) * 136 + kt * 32 + quad * 8];
            acc = __builtin_amdgcn_mfma_f32_16x16x32_f16(af[kt], bf, acc, 0, 0, 0);
        }
#pragma unroll
        for (int r = 0; r < 4; r++)
            out[(size_t)(rb + mt * 16 + quad * 4 + r) * NE + n0 + l15] = acc[r];
    }
}

extern "C" void kernel_launch(void* const* d_in, const int* in_sizes, int n_in,
                              void* d_out, int out_size, void* d_ws, size_t ws_size,
                              hipStream_t stream) {
    const float* x     = (const float*)d_in[0];
    const float* theta = (const float*)d_in[1];
    const float* w_out = (const float*)d_in[2];
    const int*   mask  = (const int*)d_in[3];
    float* out = (float*)d_out;

    // workspace: mid (2 MB) | qg (2 MB) | vtg (~2.37 MB)
    unsigned short* mid16 = (unsigned short*)d_ws;
    unsigned short* qg  = mid16 + (size_t)NB * NS * NE;            // 1,048,576 shorts
    unsigned short* vtg = qg + (size_t)NB * NH * NS * ND;          // 1,048,576 shorts

    qgen_kernel<<<NB * NH * NS / 2 / 256, 256, 0, stream>>>(x, theta, mask, qg, vtg);
    attn_kernel<<<NB * NH * 8, 512, 0, stream>>>(qg, vtg, mid16);
    proj_kernel<<<NB * NS / 32, 256, 0, stream>>>(mid16, w_out, out);
}

// Round 5
// 103.694 us; speedup vs baseline: 1.1244x; 1.0012x over previous
//
#include <hip/hip_runtime.h>
#include <hip/hip_bf16.h>
#include <hip/hip_fp16.h>

#define NB 4
#define NS 2048
#define NE 128
#define NH 16
#define ND 8

#define THALF 1024     // t rows staged per phase (2 phases)
#define NCH 32         // chunks of 32 t per phase
#define VSTRIDE 1032   // LDS vT row stride (shorts): 16B-aligned, 4-bank stagger/row
#define VGSTR 2056     // global vT row stride (shorts): 2048 + 8 pad, 16B-aligned

typedef __attribute__((ext_vector_type(8))) _Float16 half8;
typedef __attribute__((ext_vector_type(4))) _Float16 half4;
typedef __attribute__((ext_vector_type(4))) float f32x4;

__device__ __forceinline__ unsigned int pkrtz(float a, float b) {
    typedef __fp16 fp16v2 __attribute__((ext_vector_type(2)));
    union { fp16v2 h; unsigned int u; } v;
    v.h = __builtin_amdgcn_cvt_pkrtz(a, b);
    return v.u;
}
__device__ __forceinline__ unsigned short f2h(float a) {
    return __half_as_ushort(__float2half(a));   // RNE
}
__device__ __forceinline__ half8 mk_half8(unsigned u0, unsigned u1,
                                          unsigned u2, unsigned u3) {
    union { half8 h; unsigned u[4]; } v;
    v.u[0] = u0; v.u[1] = u1; v.u[2] = u2; v.u[3] = u3;
    return v.h;
}

// cumprod-of-cos row: p[d] = prod_{i<=d} cos(x[i] + th[i])
__device__ __forceinline__ void qrow(const float* __restrict__ xp,
                                     const float* th, float* p) {
    float4 a = *(const float4*)xp, c = *(const float4*)(xp + 4);
    float t = 1.f;
    t *= cosf(a.x + th[0]); p[0] = t;
    t *= cosf(a.y + th[1]); p[1] = t;
    t *= cosf(a.z + th[2]); p[2] = t;
    t *= cosf(a.w + th[3]); p[3] = t;
    t *= cosf(c.x + th[4]); p[4] = t;
    t *= cosf(c.y + th[5]); p[5] = t;
    t *= cosf(c.z + th[6]); p[6] = t;
    t *= cosf(c.w + th[7]); p[7] = t;
}

// qgen: q computed ONCE per (b,h,s). Writes:
//   qg [b][h][s][d]  f16, pre-scaled by SC  (head-major -> attn stages by memcpy)
//   vtg [b][h][9][VGSTR] f16, pi-reordered + mask-folded + ones row = the
//       exact LDS vT image (per-half columns), so attn staging is a raw copy.
__global__ __launch_bounds__(256) void qgen_kernel(
        const float* __restrict__ x,
        const float* __restrict__ theta,
        const int* __restrict__ mask,
        unsigned short* __restrict__ qg,
        unsigned short* __restrict__ vtg) {
    const int gid = blockIdx.x * 256 + threadIdx.x;   // 0..65535: (b, pair j, h)
    const int b = gid >> 14;
    const int h = gid & (NH - 1);
    const int j = (gid >> 4) & 1023;    // pair within (b,h); s0 = 2j (h fastest -> coalesced x reads)
    const int s0 = 2 * j;
    const float SC = 0.71421629f;       // sqrt(log2(e)/sqrt(8))

    float th[ND];
#pragma unroll
    for (int d = 0; d < ND; d++) th[d] = theta[d];

    float p0[ND], p1[ND];
    qrow(x + ((size_t)(b * NS + s0) * NE + h * ND), th, p0);
    qrow(x + ((size_t)(b * NS + s0 + 1) * NE + h * ND), th, p1);
    const float mz0 = mask[b * NS + s0] ? 1.f : 0.f;
    const float mz1 = mask[b * NS + s0 + 1] ? 1.f : 0.f;
    const int bh = b * NH + h;

    uint4 qa, qb;
    qa.x = pkrtz(p0[0] * SC, p0[1] * SC);
    qa.y = pkrtz(p0[2] * SC, p0[3] * SC);
    qa.z = pkrtz(p0[4] * SC, p0[5] * SC);
    qa.w = pkrtz(p0[6] * SC, p0[7] * SC);
    qb.x = pkrtz(p1[0] * SC, p1[1] * SC);
    qb.y = pkrtz(p1[2] * SC, p1[3] * SC);
    qb.z = pkrtz(p1[4] * SC, p1[5] * SC);
    qb.w = pkrtz(p1[6] * SC, p1[7] * SC);
    *(uint4*)&qg[((size_t)bh * NS + s0) * ND] = qa;
    *(uint4*)&qg[((size_t)bh * NS + s0 + 1) * ND] = qb;

    // pi position within this half: ta = 4*(i>>2)+2*(i&1)+16*((i>>1)&1) inverted
    const int H = s0 >> 10, r0 = s0 & 1023;
    const int chs = r0 >> 5, u = (r0 & 31) >> 1;
    const int i = (u & 1) | (((u >> 3) & 1) << 1) | (((u >> 1) & 3) << 2);
    const int col = H * THALF + chs * 32 + 2 * i;
    unsigned short* vb = vtg + (size_t)bh * 9 * VGSTR + col;
#pragma unroll
    for (int d = 0; d < ND; d++)
        *(unsigned int*)&vb[d * VGSTR] = pkrtz(p0[d] * mz0, p1[d] * mz1);
    *(unsigned int*)&vb[8 * VGSTR] = pkrtz(mz0, mz1);   // ones row carries mask
}

// R12: one block = one (b,h) x one SIXTEENTH of query rows (128). Grid 1024 =
// exactly 4 blocks/CU (the old 512-block grid capped residency at 2 blocks/CU
// = 4 waves/SIMD; the per-chunk dep chain ds_read->MFMA->exp2->pack->MFMA was
// latency-exposed). 8 waves x ONE m-tile (16 rows) each: bm1/O1/s01/s11/pA1
// dropped -> per-chunk work halves, VGPR falls, 8 waves/SIMD fits naturally
// (no launch_bounds cap — that's what spilled in R9).
// Phased t (2 halves re-staged into same LDS; no running-max rescale ->
// partial sums add directly). Staging is a pure coalesced uint4 copy.
//
// TRANSPOSE-FREE pipeline (verified R8): scores computed as S^T via
// mfma(A = q_t-rows, B = q_m-rows, C = 0) with 16x16x16f16 (k=16 covers the
// 8 real k; A-frag b64). x16 C-layout == x32 C-layout, so the pi-packing into
// the PV A-frag is unchanged: lane holds P[m=l15][t=tb+4*quad+r];
// pi(8q+jj)=4q+(jj&3)+16*(jj>>2); V^T rows pre-permuted by pi (in qgen).
// Ones-row at n=8 -> denominator in O column 8. bm loads once from global qg.
__global__ __launch_bounds__(512) void attn_kernel(
        const unsigned short* __restrict__ qg,
        const unsigned short* __restrict__ vtg,
        unsigned short* __restrict__ mid) {            // f16 [B*S][NE]
    __shared__ unsigned short qhl[THALF * ND + 24];    // 16,432 B (+24: A-frag overread pad)
    __shared__ unsigned short vT[9 * VSTRIDE];         // 18,576 B
                                                       // total 35,008 B -> 4 blocks/CU

    const int bid = blockIdx.x;
    const int bh = bid >> 4;
    const int b = bh >> 4, h = bh & (NH - 1);
    const int msix = bid & 15;
    const int tid = threadIdx.x;

    const int wave = tid >> 6, lane = tid & 63;
    const int quad = lane >> 4, l15 = lane & 15;
    const int mbase = msix * 128 + wave * 16;

    if (tid < 24) qhl[THALF * ND + tid] = 0;   // pad (never contributes)

    // B operand (own m rows) from global qg: 16x16x16 B-frag = 4 f16, k=quad*4+j.
    // quads 0,1 real (k=0..7); quads 2,3 zero (kills the A garbage half).
    half4 hz4 = {0, 0, 0, 0};
    const unsigned short* qmrow = qg + ((size_t)bh * NS + mbase + l15) * ND
                                + (quad < 2 ? quad * 4 : 0);
    half4 bm0 = (quad < 2) ? *(const half4*)qmrow : hz4;

    const int vrow = (l15 < 9) ? l15 : 8;
    const unsigned short* vbase = &vT[vrow * VSTRIDE];

    f32x4 O0 = {0.f, 0.f, 0.f, 0.f};
    const f32x4 zc = {0.f, 0.f, 0.f, 0.f};

    for (int p = 0; p < 2; p++) {
        // ---- stage this t-half: pure copies ----
        {   // qhl: 1024 rows x 16B = 1024 uint4, contiguous
            const uint4* qs = (const uint4*)(qg + ((size_t)bh * NS + p * THALF) * ND);
            uint4* qd = (uint4*)qhl;
            qd[tid] = qs[tid];
            qd[tid + 512] = qs[tid + 512];
        }
        {   // vT: 9 rows x 1024 shorts = 1152 uint4
            const unsigned short* vs = vtg + (size_t)bh * 9 * VGSTR + p * THALF;
            for (int jj = tid; jj < 1152; jj += 512) {
                int d = jj >> 7, c = (jj & 127) << 3;
                *(uint4*)&vT[d * VSTRIDE + c] = *(const uint4*)&vs[d * VGSTR + c];
            }
        }
        __syncthreads();

        // ---- 32 chunks of this half; O keeps accumulating across phases ----
        for (int ch = 0; ch < NCH; ch++) {
            int tb = ch * 32;
            // A operand (q_t) b64: quads 0,1 = row halves (k 0..7); quads 2,3
            // read the next row (garbage) — zeroed by B.
            half4 at0 = *(const half4*)&qhl[(tb + l15) * ND + quad * 4];
            half4 at1 = *(const half4*)&qhl[(tb + 16 + l15) * ND + quad * 4];
            half8 vf  = *(const half8*)&vbase[tb + quad * 8];

            // S^T tiles (16x16x16; C-layout identical to x32): rows t, cols m=l15
            f32x4 s00 = __builtin_amdgcn_mfma_f32_16x16x16f16(at0, bm0, zc, 0, 0, 0);
            f32x4 s10 = __builtin_amdgcn_mfma_f32_16x16x16f16(at1, bm0, zc, 0, 0, 0);

            // exp2 + in-lane pack -> PV A-frag (k-order = pi)
            half8 pA0 = mk_half8(
                pkrtz(__builtin_amdgcn_exp2f(s00[0]), __builtin_amdgcn_exp2f(s00[1])),
                pkrtz(__builtin_amdgcn_exp2f(s00[2]), __builtin_amdgcn_exp2f(s00[3])),
                pkrtz(__builtin_amdgcn_exp2f(s10[0]), __builtin_amdgcn_exp2f(s10[1])),
                pkrtz(__builtin_amdgcn_exp2f(s10[2]), __builtin_amdgcn_exp2f(s10[3])));

            O0 = __builtin_amdgcn_mfma_f32_16x16x32_f16(pA0, vf, O0, 0, 0, 0);
        }
        __syncthreads();   // all waves done reading before re-stage
    }

    // ---- epilogue: l = column 8 of O; normalize; f16 store ----
#pragma unroll
    for (int r = 0; r < 4; r++) {
        float lsum = __shfl(O0[r], (lane & 48) | 8, 64);
        float v = O0[r] / lsum;
        if (l15 < ND) {
            int m = mbase + quad * 4 + r;
            mid[(size_t)(b * NS + m) * NE + h * ND + l15] = f2h(v);
        }
    }
}

// out = mid(f16) @ w^T, f16 MFMA. Block: 32 m-rows x full N=128; 4 waves.
__global__ __launch_bounds__(256) void proj_kernel(
        const unsigned short* __restrict__ mid,
        const float* __restrict__ w,
        float* __restrict__ out) {
    __shared__ unsigned short wf[NE * 136];
    __shared__ unsigned short am[32 * 136];
    const int rb = blockIdx.x * 32;
    const int tid = threadIdx.x;

    for (int i = tid; i < 2048; i += 256) {   // wf[n][k] = f16(w[n][k])
        const float* wp = w + i * 8;
        float4 a = *(const float4*)wp, c = *(const float4*)(wp + 4);
        uint4 pk;
        pk.x = pkrtz(a.x, a.y); pk.y = pkrtz(a.z, a.w);
        pk.z = pkrtz(c.x, c.y); pk.w = pkrtz(c.z, c.w);
        int n = i >> 4, k8 = (i & 15) * 8;
        *(uint4*)&wf[n * 136 + k8] = pk;
    }
    for (int i = tid; i < 512; i += 256) {    // am[r][k] = mid[rb+r][k]
        int r = i >> 4, k8 = (i & 15) * 8;
        uint4 v = *(const uint4*)&mid[(size_t)(rb + r) * NE + k8];
        *(uint4*)&am[r * 136 + k8] = v;
    }
    __syncthreads();

    const int wave = tid >> 6, lane = tid & 63;
    const int quad = lane >> 4, l15 = lane & 15;
    const int mt = wave & 1, nh = wave >> 1;

    half8 af[4];
#pragma unroll
    for (int kt = 0; kt < 4; kt++)
        af[kt] = *(const half8*)&am[(mt * 16 + l15) * 136 + kt * 32 + quad * 8];

#pragma unroll
    for (int nt = 0; nt < 4; nt++) {
        int n0 = (nh * 4 + nt) * 16;
        f32x4 acc = {0.f, 0.f, 0.f, 0.f};
#pragma unroll
        for (int kt = 0; kt < 4; kt++) {
            half8 bf = *(const half8*)&wf[(n0 + l15) * 136 + kt * 32 + quad * 8];
            acc = __builtin_amdgcn_mfma_f32_16x16x32_f16(af[kt], bf, acc, 0, 0, 0);
        }
#pragma unroll
        for (int r = 0; r < 4; r++)
            out[(size_t)(rb + mt * 16 + quad * 4 + r) * NE + n0 + l15] = acc[r];
    }
}

extern "C" void kernel_launch(void* const* d_in, const int* in_sizes, int n_in,
                              void* d_out, int out_size, void* d_ws, size_t ws_size,
                              hipStream_t stream) {
    const float* x     = (const float*)d_in[0];
    const float* theta = (const float*)d_in[1];
    const float* w_out = (const float*)d_in[2];
    const int*   mask  = (const int*)d_in[3];
    float* out = (float*)d_out;

    // workspace: mid (2 MB) | qg (2 MB) | vtg (~2.37 MB)
    unsigned short* mid16 = (unsigned short*)d_ws;
    unsigned short* qg  = mid16 + (size_t)NB * NS * NE;            // 1,048,576 shorts
    unsigned short* vtg = qg + (size_t)NB * NH * NS * ND;          // 1,048,576 shorts

    qgen_kernel<<<NB * NH * NS / 2 / 256, 256, 0, stream>>>(x, theta, mask, qg, vtg);
    attn_kernel<<<NB * NH * 16, 512, 0, stream>>>(qg, vtg, mid16);
    proj_kernel<<<NB * NS / 32, 256, 0, stream>>>(mid16, w_out, out);
}